// Round 8
// baseline (117.028 us; speedup 1.0000x reference)
//
#include <hip/hip_runtime.h>

// Problem constants (reference: N=8192 queries, D=384, M=1024 docs)
#define N_Q   8192
#define DIM   384     // = 12 MFMA k-steps of 32
#define N_DOC 1024

typedef unsigned short ushort_t;
typedef __attribute__((ext_vector_type(8))) short bf16x8;
typedef __attribute__((ext_vector_type(4))) float f32x4;
typedef __attribute__((ext_vector_type(4))) int i32x4;

__device__ __forceinline__ float bf2f(ushort_t u) {
    union { unsigned i; float f; } c; c.i = ((unsigned)u) << 16; return c.f;
}
__device__ __forceinline__ ushort_t f2bf(float f) {   // RNE
    union { float f; unsigned u; } c; c.f = f;
    unsigned r = c.u + 0x7FFF + ((c.u >> 16) & 1);
    return (ushort_t)(r >> 16);
}

// ---------------------------------------------------------------------------
// Kernel A: row-normalize emb_q -> nq (bf16). One wave per row (384 = 64*6).
// ---------------------------------------------------------------------------
__global__ __launch_bounds__(256) void k_normalize(const float* __restrict__ emb,
                                                   ushort_t* __restrict__ nqb) {
    int w    = (blockIdx.x * 256 + threadIdx.x) >> 6;   // row
    int lane = threadIdx.x & 63;
    const float* row = emb + (size_t)w * DIM;
    float v[6];
    float ss = 0.f;
#pragma unroll
    for (int r = 0; r < 6; ++r) { v[r] = row[lane + 64 * r]; ss += v[r] * v[r]; }
#pragma unroll
    for (int off = 32; off; off >>= 1) ss += __shfl_xor(ss, off);
    float inv = rsqrtf(ss);
    ushort_t* o = nqb + (size_t)w * DIM;
#pragma unroll
    for (int r = 0; r < 6; ++r) o[lane + 64 * r] = f2bf(v[r] * inv);
}

// ---------------------------------------------------------------------------
// Kernel B: per-doc weighted segment sum -> H[j,:] (bf16), fp32 accum.
// 8 waves per doc; wave w scans queries [w*1024, (w+1)*1024); partials
// combined in LDS in fixed wave order (bit-deterministic).
// ---------------------------------------------------------------------------
#define SS_WAVES 8
__global__ __launch_bounds__(512) void k_segsum(const ushort_t* __restrict__ nqb,
                                                const float* __restrict__ label,
                                                const int*   __restrict__ ids,
                                                ushort_t* __restrict__ Hb) {
    __shared__ float pacc[SS_WAVES][DIM];
    __shared__ float pden[SS_WAVES];
    int j    = blockIdx.x;
    int lane = threadIdx.x & 63;
    int w    = threadIdx.x >> 6;
    const int span = N_Q / SS_WAVES;          // 1024
    int q0 = w * span;

    float acc[6] = {0.f, 0.f, 0.f, 0.f, 0.f, 0.f};
    float den = 0.f;

    int idc = ids[q0 + lane];
    for (int base = q0; base < q0 + span; base += 64) {
        int nb = base + 64;
        int idn = (nb < q0 + span) ? ids[nb + lane] : -1;
        unsigned long long mask = __ballot(idc == j);
        while (mask) {
            int b = __builtin_ctzll(mask);
            mask &= mask - 1;
            int q = base + b;
            float lab = label[q];
            const ushort_t* r = nqb + (size_t)q * DIM;
#pragma unroll
            for (int t = 0; t < 6; ++t) acc[t] = fmaf(lab, bf2f(r[lane + 64 * t]), acc[t]);
            den += lab;
        }
        idc = idn;
    }
#pragma unroll
    for (int t = 0; t < 6; ++t) pacc[w][lane + 64 * t] = acc[t];
    if (lane == 0) pden[w] = den;
    __syncthreads();

    int d = threadIdx.x;
    if (d < DIM) {
        float s = 0.f, dn = 0.f;
#pragma unroll
        for (int ww = 0; ww < SS_WAVES; ++ww) { s += pacc[ww][d]; dn += pden[ww]; }
        float invd = (dn > 0.f) ? (1.f / dn) : 0.f;   // empty group -> 0 (never gathered)
        Hb[(size_t)j * DIM + d] = f2bf(s * invd);
    }
}

// ---------------------------------------------------------------------------
// Kernel C (fused GEMM + expand, race-free):
//   Block = 16 output rows x all 1024 cols; 4 waves, wave w owns cols
//   [w*256, w*256+256) in 8 sub-tiles of 32 cols.
//   GEMM: B fragments loaded DIRECTLY into VGPRs (plain loads; one 64-lane
//   16B load = one 32col x 32k fragment, zero intra-wave duplication; the
//   compiler inserts all waits -> correct by construction). A-frags for all
//   12 k-steps in 48 VGPRs. Per block B traffic = 768 KB (L2-resident).
//   No LDS in the GEMM loop, no barriers -> waves free-run; other resident
//   blocks' MFMA/L2 phase hides under this block's write phase.
//   Then one barrier, gather-expand from 32 KB bf16 slab, nt f32x4 stores.
// ---------------------------------------------------------------------------
#define FR   16
#define NST  8     // 32-col sub-tiles per wave
#define NKS  12    // k-steps of 32

__global__ __launch_bounds__(256) void k_fused(const ushort_t* __restrict__ A,   // nq bf16 [N_Q][DIM]
                                               const ushort_t* __restrict__ B,   // H  bf16 [N_DOC][DIM]
                                               const int*      __restrict__ ids,
                                               float*          __restrict__ out) {
    __shared__ ushort_t slab[FR * N_DOC];    // 32 KB bf16
    int tid  = threadIdx.x;
    int lane = tid & 63, w = tid >> 6;
    int fr = lane & 15, kg = lane >> 4;
    int row0 = blockIdx.x * FR;

    // A fragments, all k-steps: row = row0+fr, k = ks*32 + kg*8 ..+8
    bf16x8 aF[NKS];
    {
        const ushort_t* Ap = A + (size_t)(row0 + fr) * DIM + kg * 8;
#pragma unroll
        for (int ks = 0; ks < NKS; ++ks) aF[ks] = *(const bf16x8*)(Ap + ks * 32);
    }

    const ushort_t* Bw = B + (size_t)(w * 256 + fr) * DIM + kg * 8;  // wave cols, lane frag base

    for (int st = 0; st < NST; ++st) {
        const ushort_t* B0 = Bw + (size_t)(st * 32) * DIM;   // cols st*32 + fr
        const ushort_t* B1 = B0 + (size_t)16 * DIM;          // cols st*32 + 16 + fr
        f32x4 acc0 = (f32x4)0.f, acc1 = (f32x4)0.f;
#pragma unroll
        for (int ks = 0; ks < NKS; ++ks) {
            bf16x8 b0 = *(const bf16x8*)(B0 + ks * 32);
            bf16x8 b1 = *(const bf16x8*)(B1 + ks * 32);
            acc0 = __builtin_amdgcn_mfma_f32_16x16x32_bf16(aF[ks], b0, acc0, 0, 0, 0);
            acc1 = __builtin_amdgcn_mfma_f32_16x16x32_bf16(aF[ks], b1, acc1, 0, 0, 0);
        }
        // dump sub-tile: C layout col = lane&15, row = (lane>>4)*4 + r  [m89]
        int c0 = w * 256 + st * 32;
#pragma unroll
        for (int r = 0; r < 4; ++r) {
            slab[(kg * 4 + r) * N_DOC + c0 + fr]      = f2bf(acc0[r]);
            slab[(kg * 4 + r) * N_DOC + c0 + 16 + fr] = f2bf(acc1[r]);
        }
    }
    __syncthreads();

    // expand: out[row0+r, q] = slab[r, ids[q]], nt f32x4 stores
    const i32x4* id4 = (const i32x4*)ids;
#pragma unroll
    for (int it = 0; it < 8; ++it) {
        int q4 = it * 256 + tid;
        i32x4 id = id4[q4];
#pragma unroll
        for (int r = 0; r < FR; ++r) {
            const ushort_t* tr = &slab[r * N_DOC];
            f32x4 v = { bf2f(tr[id.x]), bf2f(tr[id.y]), bf2f(tr[id.z]), bf2f(tr[id.w]) };
            __builtin_nontemporal_store(v, (f32x4*)(out + (size_t)(row0 + r) * N_Q) + q4);
        }
    }
}

// ---------------------------------------------------------------------------
extern "C" void kernel_launch(void* const* d_in, const int* in_sizes, int n_in,
                              void* d_out, int out_size, void* d_ws, size_t ws_size,
                              hipStream_t stream) {
    const float* emb   = (const float*)d_in[0];
    const float* label = (const float*)d_in[1];
    const int*   ids   = (const int*)d_in[2];
    float* out = (float*)d_out;

    // workspace: nqb bf16 [N_Q*DIM] | Hb bf16 [N_DOC*DIM]   (~7 MB)
    ushort_t* nqb = (ushort_t*)d_ws;
    ushort_t* Hb  = nqb + (size_t)N_Q * DIM;

    k_normalize<<<N_Q / 4, 256, 0, stream>>>(emb, nqb);
    k_segsum<<<N_DOC, 512, 0, stream>>>(nqb, label, ids, Hb);
    k_fused<<<N_Q / FR, 256, 0, stream>>>(nqb, Hb, ids, out);
}

// Round 9
// 101.547 us; speedup vs baseline: 1.1524x; 1.1524x over previous
//
#include <hip/hip_runtime.h>

// Problem constants (reference: N=8192 queries, D=384, M=1024 docs)
#define N_Q   8192
#define DIM   384     // = 6 k-iters of 64 = 12 MFMA k-steps of 32
#define N_DOC 1024

typedef unsigned short ushort_t;
typedef __attribute__((ext_vector_type(8))) short bf16x8;
typedef __attribute__((ext_vector_type(4))) float f32x4;
typedef __attribute__((ext_vector_type(4))) int i32x4;

__device__ __forceinline__ float bf2f(ushort_t u) {
    union { unsigned i; float f; } c; c.i = ((unsigned)u) << 16; return c.f;
}
__device__ __forceinline__ ushort_t f2bf(float f) {   // RNE
    union { float f; unsigned u; } c; c.f = f;
    unsigned r = c.u + 0x7FFF + ((c.u >> 16) & 1);
    return (ushort_t)(r >> 16);
}
__device__ __forceinline__ void gload_lds16(const void* g, void* l) {
    __builtin_amdgcn_global_load_lds((const __attribute__((address_space(1))) void*)g,
                                     (__attribute__((address_space(3))) void*)l, 16, 0, 0);
}

// ---------------------------------------------------------------------------
// Kernel A: row-normalize emb_q -> nq (bf16). One wave per row (384 = 64*6).
// ---------------------------------------------------------------------------
__global__ __launch_bounds__(256) void k_normalize(const float* __restrict__ emb,
                                                   ushort_t* __restrict__ nqb) {
    int w    = (blockIdx.x * 256 + threadIdx.x) >> 6;   // row
    int lane = threadIdx.x & 63;
    const float* row = emb + (size_t)w * DIM;
    float v[6];
    float ss = 0.f;
#pragma unroll
    for (int r = 0; r < 6; ++r) { v[r] = row[lane + 64 * r]; ss += v[r] * v[r]; }
#pragma unroll
    for (int off = 32; off; off >>= 1) ss += __shfl_xor(ss, off);
    float inv = rsqrtf(ss);
    ushort_t* o = nqb + (size_t)w * DIM;
#pragma unroll
    for (int r = 0; r < 6; ++r) o[lane + 64 * r] = f2bf(v[r] * inv);
}

// ---------------------------------------------------------------------------
// Kernel B: per-doc weighted segment sum -> H[j,:] (bf16), fp32 accum.
// 8 waves per doc; wave w scans queries [w*1024, (w+1)*1024); partials
// combined in LDS in fixed wave order (bit-deterministic).
// ---------------------------------------------------------------------------
#define SS_WAVES 8
__global__ __launch_bounds__(512) void k_segsum(const ushort_t* __restrict__ nqb,
                                                const float* __restrict__ label,
                                                const int*   __restrict__ ids,
                                                ushort_t* __restrict__ Hb) {
    __shared__ float pacc[SS_WAVES][DIM];
    __shared__ float pden[SS_WAVES];
    int j    = blockIdx.x;
    int lane = threadIdx.x & 63;
    int w    = threadIdx.x >> 6;
    const int span = N_Q / SS_WAVES;          // 1024
    int q0 = w * span;

    float acc[6] = {0.f, 0.f, 0.f, 0.f, 0.f, 0.f};
    float den = 0.f;

    int idc = ids[q0 + lane];
    for (int base = q0; base < q0 + span; base += 64) {
        int nb = base + 64;
        int idn = (nb < q0 + span) ? ids[nb + lane] : -1;
        unsigned long long mask = __ballot(idc == j);
        while (mask) {
            int b = __builtin_ctzll(mask);
            mask &= mask - 1;
            int q = base + b;
            float lab = label[q];
            const ushort_t* r = nqb + (size_t)q * DIM;
#pragma unroll
            for (int t = 0; t < 6; ++t) acc[t] = fmaf(lab, bf2f(r[lane + 64 * t]), acc[t]);
            den += lab;
        }
        idc = idn;
    }
#pragma unroll
    for (int t = 0; t < 6; ++t) pacc[w][lane + 64 * t] = acc[t];
    if (lane == 0) pden[w] = den;
    __syncthreads();

    int d = threadIdx.x;
    if (d < DIM) {
        float s = 0.f, dn = 0.f;
#pragma unroll
        for (int ww = 0; ww < SS_WAVES; ++ww) { s += pacc[ww][d]; dn += pden[ww]; }
        float invd = (dn > 0.f) ? (1.f / dn) : 0.f;   // empty group -> 0 (never gathered)
        Hb[(size_t)j * DIM + d] = f2bf(s * invd);
    }
}

// ---------------------------------------------------------------------------
// Kernel C (fused GEMM + expand, m97-style staged inner loop):
//   Block = FR=16 output rows x all 1024 cols; 4 waves, wave w owns cols
//   [w*32, w*32+32) of each 128-wide col-tile.
//   A-strip (16x384, 12 KB) staged ONCE via global_load_lds (XOR swizzle).
//   Per (col-tile ct, k-iter kq): stage B-tile 128x64 (16 KB) exactly like
//   R6's gemm (linear LDS dest, XOR-swizzled global source, 2 barriers) ->
//   race-free; MFMA 16x16x32, 2 acc/wave; dump col-tile into bf16 slab.
//   LDS 12+16+32 = 60 KB -> 2 blocks/CU: one block's GEMM overlaps the
//   other's write phase. Then one barrier + gather-expand with nt stores.
// ---------------------------------------------------------------------------
#define FR  16
#define CT  8     // col-tiles of 128
#define KQ  6     // k-iters of 64

__global__ __launch_bounds__(256) void k_fused(const ushort_t* __restrict__ A,   // nq bf16 [N_Q][DIM]
                                               const ushort_t* __restrict__ B,   // H  bf16 [N_DOC][DIM]
                                               const int*      __restrict__ ids,
                                               float*          __restrict__ out) {
    __shared__ ushort_t Al[FR * DIM];       // 12 KB: granule idx = kq*128 + row*8 + slot
    __shared__ ushort_t Bl[128 * 64];       // 16 KB: granule idx = col*8 + slot
    __shared__ ushort_t slab[FR * N_DOC];   // 32 KB bf16
    int tid  = threadIdx.x;
    int lane = tid & 63, w = tid >> 6;
    int fr = lane & 15, kg = lane >> 4;
    int row0 = blockIdx.x * FR;

    // ids -> registers (8 x i32x4)
    i32x4 idv[8];
    {
        const i32x4* id4 = (const i32x4*)ids;
#pragma unroll
        for (int it = 0; it < 8; ++it) idv[it] = id4[it * 256 + tid];
    }

    // stage A-strip once: 768 granules of 16 B, 3 rounds.
    // LDS slot gd holds source granule gd^(row&7)  (involutive swizzle)
#pragma unroll
    for (int r = 0; r < 3; ++r) {
        int g   = r * 256 + tid;
        int kq  = g >> 7, row = (g >> 3) & 15, gd = g & 7;
        int gs  = gd ^ (row & 7);
        gload_lds16(A + (size_t)(row0 + row) * DIM + kq * 64 + gs * 8,
                    &Al[(r * 256 + w * 64) * 8]);     // wave-uniform dest base
    }

    for (int ct = 0; ct < CT; ++ct) {
        f32x4 acc0 = (f32x4)0.f, acc1 = (f32x4)0.f;
        for (int kq = 0; kq < KQ; ++kq) {
            // stage B-tile: cols ct*128.., k kq*64..: 1024 granules, 4 rounds
#pragma unroll
            for (int r = 0; r < 4; ++r) {
                int g = r * 256 + tid;
                int row = g >> 3, gd = g & 7, gs = gd ^ (row & 7);
                gload_lds16(B + (size_t)(ct * 128 + row) * DIM + kq * 64 + gs * 8,
                            &Bl[(r * 256 + w * 64) * 8]);
            }
            __syncthreads();   // drains vmcnt -> staged data visible

#pragma unroll
            for (int ks = 0; ks < 2; ++ks) {
                int kidx = ks * 4 + kg;
                bf16x8 a  = *(const bf16x8*)&Al[(kq * 128 + fr * 8 + (kidx ^ (fr & 7))) * 8];
                int n0 = w * 32 + fr, n1 = n0 + 16;
                bf16x8 b0 = *(const bf16x8*)&Bl[(n0 * 8 + (kidx ^ (n0 & 7))) * 8];
                bf16x8 b1 = *(const bf16x8*)&Bl[(n1 * 8 + (kidx ^ (n1 & 7))) * 8];
                acc0 = __builtin_amdgcn_mfma_f32_16x16x32_bf16(a, b0, acc0, 0, 0, 0);
                acc1 = __builtin_amdgcn_mfma_f32_16x16x32_bf16(a, b1, acc1, 0, 0, 0);
            }
            __syncthreads();   // protect Bl before next restage
        }
        // dump col-tile: C layout col = lane&15 (fr), row = kg*4 + r  [m89]
        int c0 = ct * 128 + w * 32;
#pragma unroll
        for (int r = 0; r < 4; ++r) {
            slab[(kg * 4 + r) * N_DOC + c0 + fr]      = f2bf(acc0[r]);
            slab[(kg * 4 + r) * N_DOC + c0 + 16 + fr] = f2bf(acc1[r]);
        }
    }
    __syncthreads();

    // expand: out[row0+rr, q] = slab[rr, ids[q]], nt f32x4 stores
#pragma unroll
    for (int it = 0; it < 8; ++it) {
        int q4 = it * 256 + tid;
        i32x4 id = idv[it];
#pragma unroll
        for (int rr = 0; rr < FR; ++rr) {
            const ushort_t* tr = &slab[rr * N_DOC];
            f32x4 v = { bf2f(tr[id.x]), bf2f(tr[id.y]), bf2f(tr[id.z]), bf2f(tr[id.w]) };
            __builtin_nontemporal_store(v, (f32x4*)(out + (size_t)(row0 + rr) * N_Q) + q4);
        }
    }
}

// ---------------------------------------------------------------------------
extern "C" void kernel_launch(void* const* d_in, const int* in_sizes, int n_in,
                              void* d_out, int out_size, void* d_ws, size_t ws_size,
                              hipStream_t stream) {
    const float* emb   = (const float*)d_in[0];
    const float* label = (const float*)d_in[1];
    const int*   ids   = (const int*)d_in[2];
    float* out = (float*)d_out;

    // workspace: nqb bf16 [N_Q*DIM] | Hb bf16 [N_DOC*DIM]   (~7 MB)
    ushort_t* nqb = (ushort_t*)d_ws;
    ushort_t* Hb  = nqb + (size_t)N_Q * DIM;

    k_normalize<<<N_Q / 4, 256, 0, stream>>>(emb, nqb);
    k_segsum<<<N_DOC, 512, 0, stream>>>(nqb, label, ids, Hb);
    k_fused<<<N_Q / FR, 256, 0, stream>>>(nqb, Hb, ids, out);
}

// Round 10
// 75.682 us; speedup vs baseline: 1.5463x; 1.3418x over previous
//
#include <hip/hip_runtime.h>

// Problem constants (reference: N=8192 queries, D=384, M=1024 docs)
#define N_Q   8192
#define DIM   384     // = 6 k-iters of 64 = 12 MFMA k-steps of 32
#define N_DOC 1024

typedef unsigned short ushort_t;
typedef __attribute__((ext_vector_type(8))) short bf16x8;
typedef __attribute__((ext_vector_type(4))) float f32x4;
typedef __attribute__((ext_vector_type(4))) int i32x4;

__device__ __forceinline__ float bf2f(ushort_t u) {
    union { unsigned i; float f; } c; c.i = ((unsigned)u) << 16; return c.f;
}
__device__ __forceinline__ ushort_t f2bf(float f) {   // RNE
    union { float f; unsigned u; } c; c.f = f;
    unsigned r = c.u + 0x7FFF + ((c.u >> 16) & 1);
    return (ushort_t)(r >> 16);
}
__device__ __forceinline__ void gload_lds16(const void* g, void* l) {
    __builtin_amdgcn_global_load_lds((const __attribute__((address_space(1))) void*)g,
                                     (__attribute__((address_space(3))) void*)l, 16, 0, 0);
}

// ---------------------------------------------------------------------------
// Kernel A (merged normalize + segsum):
//   8 waves per doc j; wave w scans queries [w*1024, (w+1)*1024).
//   For each matched q (ids[q]==j): load RAW f32 row, normalize in-register
//   (6-elem/lane + shfl reduce — bitwise identical to old k_normalize),
//   accumulate lab*(v*inv) in f32, and write the bf16 normalized row to nqb
//   (each q matched by exactly one block/wave -> single deterministic writer).
//   Partials combined in LDS in fixed wave order (bit-deterministic).
// ---------------------------------------------------------------------------
#define SS_WAVES 8
__global__ __launch_bounds__(512) void k_segnorm(const float* __restrict__ emb,
                                                 const float* __restrict__ label,
                                                 const int*   __restrict__ ids,
                                                 ushort_t* __restrict__ nqb,
                                                 ushort_t* __restrict__ Hb) {
    __shared__ float pacc[SS_WAVES][DIM];
    __shared__ float pden[SS_WAVES];
    int j    = blockIdx.x;
    int lane = threadIdx.x & 63;
    int w    = threadIdx.x >> 6;
    const int span = N_Q / SS_WAVES;          // 1024
    int q0 = w * span;

    float acc[6] = {0.f, 0.f, 0.f, 0.f, 0.f, 0.f};
    float den = 0.f;

    int idc = ids[q0 + lane];
    for (int base = q0; base < q0 + span; base += 64) {
        int nb = base + 64;
        int idn = (nb < q0 + span) ? ids[nb + lane] : -1;
        unsigned long long mask = __ballot(idc == j);
        while (mask) {
            int b = __builtin_ctzll(mask);
            mask &= mask - 1;
            int q = base + b;
            float lab = label[q];
            const float* row = emb + (size_t)q * DIM;
            float v[6];
            float ss = 0.f;
#pragma unroll
            for (int t = 0; t < 6; ++t) { v[t] = row[lane + 64 * t]; ss += v[t] * v[t]; }
#pragma unroll
            for (int off = 32; off; off >>= 1) ss += __shfl_xor(ss, off);
            float inv = rsqrtf(ss);
            ushort_t* o = nqb + (size_t)q * DIM;
#pragma unroll
            for (int t = 0; t < 6; ++t) {
                float nv = v[t] * inv;
                acc[t] = fmaf(lab, nv, acc[t]);
                o[lane + 64 * t] = f2bf(nv);
            }
            den += lab;
        }
        idc = idn;
    }
#pragma unroll
    for (int t = 0; t < 6; ++t) pacc[w][lane + 64 * t] = acc[t];
    if (lane == 0) pden[w] = den;
    __syncthreads();

    int d = threadIdx.x;
    if (d < DIM) {
        float s = 0.f, dn = 0.f;
#pragma unroll
        for (int ww = 0; ww < SS_WAVES; ++ww) { s += pacc[ww][d]; dn += pden[ww]; }
        float invd = (dn > 0.f) ? (1.f / dn) : 0.f;   // empty group -> 0 (never gathered)
        Hb[(size_t)j * DIM + d] = f2bf(s * invd);
    }
}

// ---------------------------------------------------------------------------
// Kernel B: T[i,j] = nq[i,:] . H[j,:]  -- bf16 MFMA 16x16x32, fp32 accum,
// bf16 T output. 128x128 tile, 4 waves (2x2), wave 4x4 fragments. BK=64,
// 2-phase DOUBLE-BUFFERED staging (T3 minimum template, plain __syncthreads
// -> race-free: every wave drains vmcnt before the barrier releases):
//   stage(buf0); barrier; for kq: { stage(kq+1 -> buf^1); MFMA(buf); barrier }
// global_load_lds width-16, linear LDS dest + XOR-swizzled global source.
// ---------------------------------------------------------------------------
#define BM 128
#define BN 128
#define BK 64
#define KQ (DIM / BK)   // 6

__global__ __launch_bounds__(256) void k_gemm(const ushort_t* __restrict__ A,  // nq bf16 [N_Q][DIM]
                                              const ushort_t* __restrict__ B,  // H  bf16 [N_DOC][DIM]
                                              ushort_t* __restrict__ Tb) {     // bf16 [N_Q][N_DOC]
    __shared__ ushort_t As[2][BM * BK];   // 2 x 16 KB
    __shared__ ushort_t Bs[2][BN * BK];   // 2 x 16 KB
    int tid  = threadIdx.x;
    int lane = tid & 63, wid = tid >> 6;
    int wr = wid >> 1, wc = wid & 1;             // 2x2 wave grid
    int row0 = blockIdx.y * BM, col0 = blockIdx.x * BN;
    int fr = lane & 15, kg = lane >> 4;

    auto stage = [&](int kq, int bf) {
#pragma unroll
        for (int r = 0; r < 4; ++r) {
            int flat = r * 256 + tid;
            int row = flat >> 3, gd = flat & 7;
            int gs = gd ^ (row & 7);                     // involutive source swizzle
            int wbase = (r * 256 + wid * 64) * 8;        // wave-uniform LDS elem base
            gload_lds16(A + (size_t)(row0 + row) * DIM + kq * BK + gs * 8, &As[bf][wbase]);
            gload_lds16(B + (size_t)(col0 + row) * DIM + kq * BK + gs * 8, &Bs[bf][wbase]);
        }
    };

    f32x4 acc[4][4];
#pragma unroll
    for (int i = 0; i < 4; ++i)
#pragma unroll
        for (int j = 0; j < 4; ++j) acc[i][j] = (f32x4)0.f;

    stage(0, 0);
    __syncthreads();                 // buf0 staged (vmcnt drained by barrier)
    int cur = 0;
    for (int kq = 0; kq < KQ; ++kq) {
        if (kq + 1 < KQ) stage(kq + 1, cur ^ 1);   // in flight during MFMA

#pragma unroll
        for (int ks = 0; ks < 2; ++ks) {                 // two k=32 steps per BK=64
            bf16x8 a[4], b[4];
#pragma unroll
            for (int mi = 0; mi < 4; ++mi) {
                int m = wr * 64 + mi * 16 + fr;
                a[mi] = *(const bf16x8*)&As[cur][m * 64 + (((ks * 4 + kg) ^ (m & 7)) << 3)];
            }
#pragma unroll
            for (int ni = 0; ni < 4; ++ni) {
                int n = wc * 64 + ni * 16 + fr;
                b[ni] = *(const bf16x8*)&Bs[cur][n * 64 + (((ks * 4 + kg) ^ (n & 7)) << 3)];
            }
#pragma unroll
            for (int mi = 0; mi < 4; ++mi)
#pragma unroll
                for (int ni = 0; ni < 4; ++ni)
                    acc[mi][ni] = __builtin_amdgcn_mfma_f32_16x16x32_bf16(a[mi], b[ni], acc[mi][ni], 0, 0, 0);
        }
        __syncthreads();             // drains: next buf's loads + this buf's ds_reads
        cur ^= 1;
    }

    // C/D layout: col = lane&15, row = (lane>>4)*4 + reg   [m89]
#pragma unroll
    for (int mi = 0; mi < 4; ++mi)
#pragma unroll
        for (int ni = 0; ni < 4; ++ni)
#pragma unroll
            for (int r = 0; r < 4; ++r)
                Tb[(size_t)(row0 + wr * 64 + mi * 16 + kg * 4 + r) * N_DOC
                   + col0 + wc * 64 + ni * 16 + fr] = f2bf(acc[mi][ni][r]);
}

// ---------------------------------------------------------------------------
// Kernel C: out[i,q] = T[i, ids[q]].  8 rows/block (1024 blocks = 4/CU).
// ids held in registers; 8 bf16 T-rows converted to f32 in 32 KB LDS;
// non-temporal f32x4 stores (write-BW bound, no L2 pollution).
// ---------------------------------------------------------------------------
#define EROWS 8
__global__ __launch_bounds__(256) void k_expand(const ushort_t* __restrict__ Tb,
                                                const int*      __restrict__ ids,
                                                float*          __restrict__ out) {
    __shared__ float trow[EROWS * N_DOC];   // 32 KB
    int tid = threadIdx.x;
    int i0  = blockIdx.x * EROWS;

    // ids -> registers (8 x i32x4 per thread)
    i32x4 idv[N_Q / 4 / 256];
    const i32x4* id4 = (const i32x4*)ids;
#pragma unroll
    for (int it = 0; it < N_Q / 4 / 256; ++it) idv[it] = id4[it * 256 + tid];

    // stage 8 bf16 rows -> f32 LDS (1024 chunks of 16 B)
    const bf16x8* Tv = (const bf16x8*)(Tb + (size_t)i0 * N_DOC);
#pragma unroll
    for (int c = 0; c < 4; ++c) {
        int chunk = c * 256 + tid;
        bf16x8 v = Tv[chunk];
        f32x4 lo = { bf2f((ushort_t)v[0]), bf2f((ushort_t)v[1]), bf2f((ushort_t)v[2]), bf2f((ushort_t)v[3]) };
        f32x4 hi = { bf2f((ushort_t)v[4]), bf2f((ushort_t)v[5]), bf2f((ushort_t)v[6]), bf2f((ushort_t)v[7]) };
        *(f32x4*)&trow[chunk * 8]     = lo;
        *(f32x4*)&trow[chunk * 8 + 4] = hi;
    }
    __syncthreads();

#pragma unroll
    for (int it = 0; it < N_Q / 4 / 256; ++it) {   // 8 iterations over q
        int q4 = it * 256 + tid;
        i32x4 id = idv[it];
#pragma unroll
        for (int r = 0; r < EROWS; ++r) {
            const float* tr = &trow[r * N_DOC];
            f32x4 v = { tr[id.x], tr[id.y], tr[id.z], tr[id.w] };
            __builtin_nontemporal_store(v, (f32x4*)(out + (size_t)(i0 + r) * N_Q) + q4);
        }
    }
}

// ---------------------------------------------------------------------------
extern "C" void kernel_launch(void* const* d_in, const int* in_sizes, int n_in,
                              void* d_out, int out_size, void* d_ws, size_t ws_size,
                              hipStream_t stream) {
    const float* emb   = (const float*)d_in[0];
    const float* label = (const float*)d_in[1];
    const int*   ids   = (const int*)d_in[2];
    float* out = (float*)d_out;

    // workspace: nqb bf16 [N_Q*DIM] | Hb bf16 [N_DOC*DIM] | Tb bf16 [N_Q*N_DOC]
    ushort_t* nqb = (ushort_t*)d_ws;
    ushort_t* Hb  = nqb + (size_t)N_Q * DIM;
    ushort_t* Tb  = Hb + (size_t)N_DOC * DIM;

    k_segnorm<<<N_DOC, 512, 0, stream>>>(emb, label, ids, nqb, Hb);
    k_gemm<<<dim3(N_DOC / BN, N_Q / BM), 256, 0, stream>>>(nqb, Hb, Tb);
    k_expand<<<N_Q / EROWS, 256, 0, stream>>>(Tb, ids, out);
}

// Round 12
// 74.920 us; speedup vs baseline: 1.5620x; 1.0102x over previous
//
#include <hip/hip_runtime.h>

// Problem constants (reference: N=8192 queries, D=384, M=1024 docs)
#define N_Q   8192
#define DIM   384     // = 6 k-iters of 64 = 12 MFMA k-steps of 32
#define N_DOC 1024

typedef unsigned short ushort_t;
typedef __attribute__((ext_vector_type(8))) short bf16x8;
typedef __attribute__((ext_vector_type(4))) float f32x4;
typedef __attribute__((ext_vector_type(4))) int i32x4;

__device__ __forceinline__ float bf2f(ushort_t u) {
    union { unsigned i; float f; } c; c.i = ((unsigned)u) << 16; return c.f;
}
__device__ __forceinline__ ushort_t f2bf(float f) {   // RNE
    union { float f; unsigned u; } c; c.f = f;
    unsigned r = c.u + 0x7FFF + ((c.u >> 16) & 1);
    return (ushort_t)(r >> 16);
}
__device__ __forceinline__ void gload_lds16(const void* g, void* l) {
    __builtin_amdgcn_global_load_lds((const __attribute__((address_space(1))) void*)g,
                                     (__attribute__((address_space(3))) void*)l, 16, 0, 0);
}

// ---------------------------------------------------------------------------
// Kernel A (merged normalize + segsum):
//   8 waves per doc j; wave w scans queries [w*1024, (w+1)*1024).
//   For each matched q: load RAW f32 row, normalize in-register, accumulate
//   lab*(v*inv) in f32, write bf16 normalized row to nqb (single writer).
//   Partials combined in LDS in fixed wave order (bit-deterministic).
// ---------------------------------------------------------------------------
#define SS_WAVES 8
__global__ __launch_bounds__(512) void k_segnorm(const float* __restrict__ emb,
                                                 const float* __restrict__ label,
                                                 const int*   __restrict__ ids,
                                                 ushort_t* __restrict__ nqb,
                                                 ushort_t* __restrict__ Hb) {
    __shared__ float pacc[SS_WAVES][DIM];
    __shared__ float pden[SS_WAVES];
    int j    = blockIdx.x;
    int lane = threadIdx.x & 63;
    int w    = threadIdx.x >> 6;
    const int span = N_Q / SS_WAVES;          // 1024
    int q0 = w * span;

    float acc[6] = {0.f, 0.f, 0.f, 0.f, 0.f, 0.f};
    float den = 0.f;

    int idc = ids[q0 + lane];
    for (int base = q0; base < q0 + span; base += 64) {
        int nb = base + 64;
        int idn = (nb < q0 + span) ? ids[nb + lane] : -1;
        unsigned long long mask = __ballot(idc == j);
        while (mask) {
            int b = __builtin_ctzll(mask);
            mask &= mask - 1;
            int q = base + b;
            float lab = label[q];
            const float* row = emb + (size_t)q * DIM;
            float v[6];
            float ss = 0.f;
#pragma unroll
            for (int t = 0; t < 6; ++t) { v[t] = row[lane + 64 * t]; ss += v[t] * v[t]; }
#pragma unroll
            for (int off = 32; off; off >>= 1) ss += __shfl_xor(ss, off);
            float inv = rsqrtf(ss);
            ushort_t* o = nqb + (size_t)q * DIM;
#pragma unroll
            for (int t = 0; t < 6; ++t) {
                float nv = v[t] * inv;
                acc[t] = fmaf(lab, nv, acc[t]);
                o[lane + 64 * t] = f2bf(nv);
            }
            den += lab;
        }
        idc = idn;
    }
#pragma unroll
    for (int t = 0; t < 6; ++t) pacc[w][lane + 64 * t] = acc[t];
    if (lane == 0) pden[w] = den;
    __syncthreads();

    int d = threadIdx.x;
    if (d < DIM) {
        float s = 0.f, dn = 0.f;
#pragma unroll
        for (int ww = 0; ww < SS_WAVES; ++ww) { s += pacc[ww][d]; dn += pden[ww]; }
        float invd = (dn > 0.f) ? (1.f / dn) : 0.f;   // empty group -> 0 (never gathered)
        Hb[(size_t)j * DIM + d] = f2bf(s * invd);
    }
}

// ---------------------------------------------------------------------------
// Kernel B: T[i,j] = nq[i,:] . H[j,:]  -- bf16 MFMA 16x16x32, fp32 accum,
// bf16 output. 128x64 tile -> 1024 blocks (4/CU, full machine). 4 waves;
// wave w owns rows [w*32, w*32+32) x all 64 cols (2 m-frags x 4 n-frags).
// Single-buffered 2-barrier staging (proven race-free); XOR-swizzled
// global_load_lds width-16; TLP from 4 blocks/CU hides staging latency.
// ---------------------------------------------------------------------------
__global__ __launch_bounds__(256) void k_gemm(const ushort_t* __restrict__ A,  // nq bf16 [N_Q][DIM]
                                              const ushort_t* __restrict__ B,  // H  bf16 [N_DOC][DIM]
                                              ushort_t* __restrict__ Tb) {     // bf16 [N_Q][N_DOC]
    __shared__ ushort_t As[128 * 64];   // 16 KB: elem offset = (row*8 + slot)*8
    __shared__ ushort_t Bs[64 * 64];    //  8 KB
    int tid  = threadIdx.x;
    int lane = tid & 63, w = tid >> 6;
    int row0 = blockIdx.y * 128, col0 = blockIdx.x * 64;
    int fr = lane & 15, kg = lane >> 4;

    f32x4 acc[2][4];
#pragma unroll
    for (int i = 0; i < 2; ++i)
#pragma unroll
        for (int jj = 0; jj < 4; ++jj) acc[i][jj] = (f32x4)0.f;

    for (int kq = 0; kq < 6; ++kq) {
        // stage A-tile 128x64: 1024 granules of 16 B, 4 rounds
#pragma unroll
        for (int r = 0; r < 4; ++r) {
            int flat = r * 256 + tid;
            int row = flat >> 3, gd = flat & 7, gs = gd ^ (row & 7);
            gload_lds16(A + (size_t)(row0 + row) * DIM + kq * 64 + gs * 8,
                        &As[(r * 256 + w * 64) * 8]);
        }
        // stage B-tile 64x64: 512 granules, 2 rounds
#pragma unroll
        for (int r = 0; r < 2; ++r) {
            int flat = r * 256 + tid;
            int row = flat >> 3, gd = flat & 7, gs = gd ^ (row & 7);
            gload_lds16(B + (size_t)(col0 + row) * DIM + kq * 64 + gs * 8,
                        &Bs[(r * 256 + w * 64) * 8]);
        }
        __syncthreads();   // drains vmcnt -> staged data visible

#pragma unroll
        for (int ks = 0; ks < 2; ++ks) {
            int kidx = ks * 4 + kg;
            bf16x8 a[2], b[4];
#pragma unroll
            for (int mi = 0; mi < 2; ++mi) {
                int m = w * 32 + mi * 16 + fr;
                a[mi] = *(const bf16x8*)&As[(m * 8 + (kidx ^ (m & 7))) * 8];
            }
#pragma unroll
            for (int ni = 0; ni < 4; ++ni) {
                int n = ni * 16 + fr;
                b[ni] = *(const bf16x8*)&Bs[(n * 8 + (kidx ^ (n & 7))) * 8];
            }
#pragma unroll
            for (int mi = 0; mi < 2; ++mi)
#pragma unroll
                for (int ni = 0; ni < 4; ++ni)
                    acc[mi][ni] = __builtin_amdgcn_mfma_f32_16x16x32_bf16(a[mi], b[ni], acc[mi][ni], 0, 0, 0);
        }
        __syncthreads();   // protect As/Bs before restage
    }

    // C/D layout: col = lane&15, row = (lane>>4)*4 + reg   [m89]
#pragma unroll
    for (int mi = 0; mi < 2; ++mi)
#pragma unroll
        for (int ni = 0; ni < 4; ++ni)
#pragma unroll
            for (int rr = 0; rr < 4; ++rr)
                Tb[(size_t)(row0 + w * 32 + mi * 16 + kg * 4 + rr) * N_DOC
                   + col0 + ni * 16 + fr] = f2bf(acc[mi][ni][rr]);
}

// ---------------------------------------------------------------------------
// Kernel C: out[i,q] = T[i, ids[q]].  8 rows/block (1024 blocks = 4/CU).
// ids held in registers; 8 bf16 T-rows converted to f32 in 32 KB LDS;
// non-temporal f32x4 stores (write-BW bound, no L2 pollution).
// ---------------------------------------------------------------------------
#define EROWS 8
__global__ __launch_bounds__(256) void k_expand(const ushort_t* __restrict__ Tb,
                                                const int*      __restrict__ ids,
                                                float*          __restrict__ out) {
    __shared__ float trow[EROWS * N_DOC];   // 32 KB
    int tid = threadIdx.x;
    int i0  = blockIdx.x * EROWS;

    // ids -> registers (8 x i32x4 per thread)
    i32x4 idv[N_Q / 4 / 256];
    const i32x4* id4 = (const i32x4*)ids;
#pragma unroll
    for (int it = 0; it < N_Q / 4 / 256; ++it) idv[it] = id4[it * 256 + tid];

    // stage 8 bf16 rows -> f32 LDS (1024 chunks of 16 B)
    const bf16x8* Tv = (const bf16x8*)(Tb + (size_t)i0 * N_DOC);
#pragma unroll
    for (int c = 0; c < 4; ++c) {
        int chunk = c * 256 + tid;
        bf16x8 v = Tv[chunk];
        f32x4 lo = { bf2f((ushort_t)v[0]), bf2f((ushort_t)v[1]), bf2f((ushort_t)v[2]), bf2f((ushort_t)v[3]) };
        f32x4 hi = { bf2f((ushort_t)v[4]), bf2f((ushort_t)v[5]), bf2f((ushort_t)v[6]), bf2f((ushort_t)v[7]) };
        *(f32x4*)&trow[chunk * 8]     = lo;
        *(f32x4*)&trow[chunk * 8 + 4] = hi;
    }
    __syncthreads();

#pragma unroll
    for (int it = 0; it < N_Q / 4 / 256; ++it) {   // 8 iterations over q
        int q4 = it * 256 + tid;
        i32x4 id = idv[it];
#pragma unroll
        for (int r = 0; r < EROWS; ++r) {
            const float* tr = &trow[r * N_DOC];
            f32x4 v = { tr[id.x], tr[id.y], tr[id.z], tr[id.w] };
            __builtin_nontemporal_store(v, (f32x4*)(out + (size_t)(i0 + r) * N_Q) + q4);
        }
    }
}

// ---------------------------------------------------------------------------
extern "C" void kernel_launch(void* const* d_in, const int* in_sizes, int n_in,
                              void* d_out, int out_size, void* d_ws, size_t ws_size,
                              hipStream_t stream) {
    const float* emb   = (const float*)d_in[0];
    const float* label = (const float*)d_in[1];
    const int*   ids   = (const int*)d_in[2];
    float* out = (float*)d_out;

    // workspace: nqb bf16 [N_Q*DIM] | Hb bf16 [N_DOC*DIM] | Tb bf16 [N_Q*N_DOC]
    ushort_t* nqb = (ushort_t*)d_ws;
    ushort_t* Hb  = nqb + (size_t)N_Q * DIM;
    ushort_t* Tb  = Hb + (size_t)N_DOC * DIM;

    k_segnorm<<<N_DOC, 512, 0, stream>>>(emb, label, ids, nqb, Hb);
    k_gemm<<<dim3(N_DOC / 64, N_Q / 128), 256, 0, stream>>>(nqb, Hb, Tb);
    k_expand<<<N_Q / EROWS, 256, 0, stream>>>(Tb, ids, out);
}